// Round 14
// baseline (399.028 us; speedup 1.0000x reference)
//
#include <hip/hip_runtime.h>
#include <hip/hip_bf16.h>

#define B_DIM   16384
#define D_IN    1024
#define D_EXP   1024
#define D_TOW   512
#define N_EXPT  8
#define N_TASK  4

typedef _Float16 f16x8 __attribute__((ext_vector_type(8)));
typedef _Float16 f16x4 __attribute__((ext_vector_type(4)));
typedef float    f32x4 __attribute__((ext_vector_type(4)));

// ---------------- async global->LDS (16B per lane, wave-uniform LDS base) ---
__device__ __forceinline__ void gll16(const void* g, void* l) {
  __builtin_amdgcn_global_load_lds(
      (const __attribute__((address_space(1))) unsigned int*)g,
      (__attribute__((address_space(3))) unsigned int*)l,
      16, 0, 0);
}

// Fragment read from a swizzled [rows][64] f16 LDS tile (16x16x32 mapping).
// 16B chunk s within a 128B row holds global chunk s^(row&7).
__device__ __forceinline__ f16x8 ldfrag(const _Float16* sM, int rowbase, int ks, int lane) {
  int rl = rowbase + (lane & 15);
  int ch = ((ks << 2) + (lane >> 4)) ^ (rl & 7);
  return *(const f16x8*)&sM[rl * 64 + ch * 8];
}

#define FENCE asm volatile("" ::: "memory")

// ---------------- prep: x -> f16, gates = x @ gate_w (fp32) ----------------
__global__ __launch_bounds__(256) void prep_x_kernel(
    const float* __restrict__ x, const float* __restrict__ gw,
    _Float16* __restrict__ xh, float* __restrict__ gates)
{
  __shared__ float sred[4][8];
  const int t = threadIdx.x;
  const long row = blockIdx.x;
  float4 v = ((const float4*)(x + row * D_IN))[t];
  f16x4 h;
  h[0] = (_Float16)v.x; h[1] = (_Float16)v.y; h[2] = (_Float16)v.z; h[3] = (_Float16)v.w;
  ((f16x4*)(xh + row * D_IN))[t] = h;

  float g[8];
#pragma unroll
  for (int e = 0; e < 8; ++e) g[e] = 0.f;
  const float* wp = gw + (size_t)t * 4 * 8;
  float xs[4] = {v.x, v.y, v.z, v.w};
#pragma unroll
  for (int j = 0; j < 4; ++j)
#pragma unroll
    for (int e = 0; e < 8; ++e) g[e] += xs[j] * wp[j * 8 + e];

#pragma unroll
  for (int e = 0; e < 8; ++e) {
    g[e] += __shfl_xor(g[e], 1);  g[e] += __shfl_xor(g[e], 2);
    g[e] += __shfl_xor(g[e], 4);  g[e] += __shfl_xor(g[e], 8);
    g[e] += __shfl_xor(g[e], 16); g[e] += __shfl_xor(g[e], 32);
  }
  if ((t & 63) == 0) {
#pragma unroll
    for (int e = 0; e < 8; ++e) sred[t >> 6][e] = g[e];
  }
  __syncthreads();
  if (t < 8) gates[row * 8 + t] = sred[0][t] + sred[1][t] + sred[2][t] + sred[3][t];
}

// ---------------- tiled transpose + fp32->f16: in[s][K][N] -> out[s][N][K] --
__global__ __launch_bounds__(256) void transpose_cvt_kernel(
    const float* __restrict__ in, _Float16* __restrict__ outp, int K, int N)
{
  __shared__ float tile[64][65];
  const int t = threadIdx.x;
  const int tx = t & 63, ty = t >> 6;
  const int n0 = blockIdx.x * 64;
  const int k0 = blockIdx.y * 64;
  const long s = blockIdx.z;
  const float* ip = in + s * (long)K * N;
  _Float16* op = outp + s * (long)K * N;
#pragma unroll
  for (int i = 0; i < 16; ++i) {
    int r = ty * 16 + i;
    tile[r][tx] = ip[(long)(k0 + r) * N + n0 + tx];
  }
  __syncthreads();
#pragma unroll
  for (int i = 0; i < 16; ++i) {
    int r = ty * 16 + i;
    op[(long)(n0 + r) * K + k0 + tx] = (_Float16)tile[tx][r];
  }
}

// ---------------- init d_out with tb2 --------------------------------------
__global__ void init_out_kernel(float* __restrict__ out, const float* __restrict__ tb2) {
  int i = blockIdx.x * 256 + threadIdx.x;
  if (i < N_TASK * B_DIM) out[i] = tb2[i >> 14];
}

// ============ expert-pair kernel: BM=128, single slot, 2 blocks/CU ==========
// 256 threads = 4 waves (2M x 2N); per-wave C = 64x64 PER EXPERT, two experts
// resident. 64 MFMA / 24 ds_read per K-tile per wave. Single 48KB slot ->
// 54KB LDS -> 2 independent blocks/CU (m114 cross-block overlap covers the
// exposed vmcnt(0)). Slot bytes: A[128x64]@0, B0[128x64]@16384, B1@32768.

#define LD_AF                                                                  \
    _Pragma("unroll") for (int mf = 0; mf < 4; ++mf)                           \
      _Pragma("unroll") for (int ks = 0; ks < 2; ++ks)                         \
        af[mf][ks] = ldfrag(sA, mf * 16, ks, lane)

#define LD_BF(SB)                                                              \
    _Pragma("unroll") for (int nf = 0; nf < 4; ++nf)                           \
      _Pragma("unroll") for (int ks = 0; ks < 2; ++ks)                         \
        bf[nf][ks] = ldfrag(SB, nf * 16, ks, lane)

#define MFMA32(ACC)                                                            \
    _Pragma("unroll") for (int mf = 0; mf < 4; ++mf)                           \
      _Pragma("unroll") for (int nf = 0; nf < 4; ++nf)                         \
        _Pragma("unroll") for (int ks = 0; ks < 2; ++ks)                       \
          ACC[mf][nf] = __builtin_amdgcn_mfma_f32_16x16x32_f16(                \
              af[mf][ks], bf[nf][ks], ACC[mf][nf], 0, 0, 0)

// ---------------- fused experts + gate-weighted combine ---------------------
// shared[b,d] = sum_e gates[b,e] * relu(x[b,:] @ exp_w[e,:,d] + exp_b[e,d])
__global__ __launch_bounds__(256, 2) void moe_expert_kernel(
    const _Float16* __restrict__ xh,    // [B,1024]
    const _Float16* __restrict__ ewT,   // [8][n=1024][k=1024]
    const float* __restrict__ expb,     // [8][1024]
    const float* __restrict__ gates,    // [B][8]
    _Float16* __restrict__ shout)       // [B,1024] f16
{
  __shared__ alignas(16) _Float16 sT[24576];      // 48KB single slot
  __shared__ float sG[128 * 8];                   // 4KB
  __shared__ _Float16 sBiasH[8 * 128];            // 2KB
  const int t = threadIdx.x;
  const int lane = t & 63;
  const int wave = t >> 6;
  const int wm = wave >> 1, wn = wave & 1;        // 2M x 2N
  const long row0 = (long)blockIdx.x * 128;
  const int col0 = blockIdx.y * 128;

  for (int i = t; i < 128 * 8; i += 256) sG[i] = gates[row0 * 8 + i];
  for (int i = t; i < 8 * 128; i += 256)
    sBiasH[i] = (_Float16)expb[(i >> 7) * D_EXP + col0 + (i & 127)];

  const int so_t = (((t & 7) ^ ((t >> 3) & 7)) << 4);
  const char* aBase = (const char*)xh + row0 * 2048 + (size_t)(t >> 3) * 2048 + so_t;
  const char* bRoot = (const char*)ewT + (size_t)col0 * 2048 + (size_t)(t >> 3) * 2048 + so_t;

  // A tile 16KB: 4 sweeps of 32 rows; 256 threads x 16B = 4KB/sweep
  auto SA = [&](int kt) {
    const char* g = aBase + (size_t)(kt & 15) * 128;
    char* d = (char*)&sT[0] + t * 16;
    gll16(g, d);                 gll16(g + 65536, d + 4096);
    gll16(g + 131072, d + 8192); gll16(g + 196608, d + 12288);
    FENCE;
  };
  auto SB = [&](int eloc, int e, int kt) {        // one expert's B: 16KB
    const char* g = bRoot + (size_t)e * 2097152 + (size_t)(kt & 15) * 128;
    char* d = (char*)&sT[0] + 16384 + eloc * 16384 + t * 16;
    gll16(g, d);                 gll16(g + 65536, d + 4096);
    gll16(g + 131072, d + 8192); gll16(g + 196608, d + 12288);
    FENCE;
  };
  auto STAGE = [&](int tau) {
    const int ep = tau >> 4, kt = tau & 15;
    SA(kt);
    SB(0, 2 * ep, kt);
    SB(1, 2 * ep + 1, kt);
  };

  __syncthreads();   // sG/sBias visible; vmcnt fully drained

  STAGE(0);
  asm volatile("s_waitcnt vmcnt(0)" ::: "memory");
  __builtin_amdgcn_s_barrier();
  FENCE;

  f32x4 acc0[4][4] = {};
  f32x4 acc1[4][4] = {};
  f16x4 shacc[4][4] = {};
  f16x8 af[4][2], bf[4][2];

  const _Float16* sA  = &sT[wm * 4096];
  const _Float16* sB0 = &sT[8192 + wn * 4096];
  const _Float16* sB1 = &sT[16384 + wn * 4096];

  for (int tau = 0; tau < 64; ++tau) {
    LD_AF; LD_BF(sB0);
    __builtin_amdgcn_s_setprio(1);
    MFMA32(acc0);
    __builtin_amdgcn_s_setprio(0);
    LD_BF(sB1);
    asm volatile("s_waitcnt lgkmcnt(0)" ::: "memory");
    __builtin_amdgcn_sched_barrier(0);
    FENCE;
    __builtin_amdgcn_s_barrier();        // all waves done reading slot
    FENCE;
    if (tau < 63) STAGE(tau + 1);        // overlaps acc1 MFMA cluster
    __builtin_amdgcn_s_setprio(1);
    MFMA32(acc1);
    __builtin_amdgcn_s_setprio(0);
    FENCE;
    if (tau < 63) {
      asm volatile("s_waitcnt vmcnt(0)" ::: "memory");
      __builtin_amdgcn_s_barrier();
      FENCE;
    }

    if ((tau & 15) == 15) {              // expert-pair boundary: combine
      const int e0 = (tau >> 4) * 2;
#pragma unroll
      for (int ee = 0; ee < 2; ++ee) {
        const int e = e0 + ee;
        float bias4[4];
#pragma unroll
        for (int nf = 0; nf < 4; ++nf)
          bias4[nf] = (float)sBiasH[e * 128 + wn * 64 + nf * 16 + (lane & 15)];
#pragma unroll
        for (int mf = 0; mf < 4; ++mf) {
          int rbase = wm * 64 + mf * 16 + ((lane >> 4) << 2);
          float gv[4];
#pragma unroll
          for (int r = 0; r < 4; ++r) gv[r] = sG[(rbase + r) * 8 + e];
#pragma unroll
          for (int nf = 0; nf < 4; ++nf) {
            f16x4 sh = shacc[mf][nf];
#pragma unroll
            for (int r = 0; r < 4; ++r) {
              float hv = (ee ? acc1[mf][nf][r] : acc0[mf][nf][r]) + bias4[nf];
              hv = hv > 0.f ? hv : 0.f;
              sh[r] += (_Float16)(gv[r] * hv);
              if (ee) acc1[mf][nf][r] = 0.f; else acc0[mf][nf][r] = 0.f;
            }
            shacc[mf][nf] = sh;
          }
        }
      }
    }
  }

  // write shared tile as f16
#pragma unroll
  for (int mf = 0; mf < 4; ++mf)
#pragma unroll
    for (int r = 0; r < 4; ++r) {
      long row = row0 + wm * 64 + mf * 16 + ((lane >> 4) << 2) + r;
      _Float16* op = shout + row * D_EXP + col0 + wn * 64 + (lane & 15);
#pragma unroll
      for (int nf = 0; nf < 4; ++nf) op[nf * 16] = shacc[mf][nf][r];
    }
}

// ---------------- fused towers (2 tasks resident, shared A) -----------------
// out[task,b] += sum_h relu(shared[b,:] @ tw1[task,:,h] + tb1[task,h]) * tw2[task,h]
// Grid (128, 8): tp = y>>2 (tasks 2tp,2tp+1), col0 = (y&3)*128. 2 blocks/CU.
__global__ __launch_bounds__(256, 2) void moe_tower_kernel(
    const _Float16* __restrict__ sh,    // [B,1024] f16
    const _Float16* __restrict__ t1T,   // [4][h=512][d=1024] f16
    const float* __restrict__ tb1,      // [4][512]
    const float* __restrict__ tw2,      // [4][512]
    float* __restrict__ out)            // [4][B]
{
  __shared__ alignas(16) _Float16 sT[24576];      // 48KB single slot
  const int t = threadIdx.x;
  const int lane = t & 63;
  const int wave = t >> 6;
  const int wm = wave >> 1, wn = wave & 1;
  const long row0 = (long)blockIdx.x * 128;
  const int tp = blockIdx.y >> 2;                 // 0..1
  const int col0 = (blockIdx.y & 3) * 128;

  float b1[2][4], w2[2][4];
#pragma unroll
  for (int ee = 0; ee < 2; ++ee)
#pragma unroll
    for (int nf = 0; nf < 4; ++nf) {
      int col = col0 + wn * 64 + nf * 16 + (lane & 15);
      b1[ee][nf] = tb1[(2 * tp + ee) * D_TOW + col];
      w2[ee][nf] = tw2[(2 * tp + ee) * D_TOW + col];
    }
  asm volatile("s_waitcnt vmcnt(0)" ::: "memory");  // clean FIFO

  const int so_t = (((t & 7) ^ ((t >> 3) & 7)) << 4);
  const char* aBase = (const char*)sh + row0 * 2048 + (size_t)(t >> 3) * 2048 + so_t;
  const char* bRoot = (const char*)t1T + (size_t)col0 * 2048
                      + (size_t)(t >> 3) * 2048 + so_t;

  auto SA = [&](int kt) {
    const char* g = aBase + (size_t)kt * 128;
    char* d = (char*)&sT[0] + t * 16;
    gll16(g, d);                 gll16(g + 65536, d + 4096);
    gll16(g + 131072, d + 8192); gll16(g + 196608, d + 12288);
    FENCE;
  };
  auto SB = [&](int eloc, int task, int kt) {
    const char* g = bRoot + (size_t)task * 1048576 + (size_t)kt * 128;
    char* d = (char*)&sT[0] + 16384 + eloc * 16384 + t * 16;
    gll16(g, d);                 gll16(g + 65536, d + 4096);
    gll16(g + 131072, d + 8192); gll16(g + 196608, d + 12288);
    FENCE;
  };
  auto STAGE = [&](int kt) {
    SA(kt);
    SB(0, 2 * tp, kt);
    SB(1, 2 * tp + 1, kt);
  };

  __syncthreads();

  STAGE(0);
  asm volatile("s_waitcnt vmcnt(0)" ::: "memory");
  __builtin_amdgcn_s_barrier();
  FENCE;

  f32x4 acc0[4][4] = {};
  f32x4 acc1[4][4] = {};
  f16x8 af[4][2], bf[4][2];

  const _Float16* sA  = &sT[wm * 4096];
  const _Float16* sB0 = &sT[8192 + wn * 4096];
  const _Float16* sB1 = &sT[16384 + wn * 4096];

  for (int kt = 0; kt < 16; ++kt) {
    LD_AF; LD_BF(sB0);
    __builtin_amdgcn_s_setprio(1);
    MFMA32(acc0);
    __builtin_amdgcn_s_setprio(0);
    LD_BF(sB1);
    asm volatile("s_waitcnt lgkmcnt(0)" ::: "memory");
    __builtin_amdgcn_sched_barrier(0);
    FENCE;
    __builtin_amdgcn_s_barrier();
    FENCE;
    if (kt < 15) STAGE(kt + 1);
    __builtin_amdgcn_s_setprio(1);
    MFMA32(acc1);
    __builtin_amdgcn_s_setprio(0);
    FENCE;
    if (kt < 15) {
      asm volatile("s_waitcnt vmcnt(0)" ::: "memory");
      __builtin_amdgcn_s_barrier();
      FENCE;
    }
  }

#pragma unroll
  for (int mf = 0; mf < 4; ++mf)
#pragma unroll
    for (int r = 0; r < 4; ++r) {
#pragma unroll
      for (int ee = 0; ee < 2; ++ee) {
        float ssum = 0.f;
#pragma unroll
        for (int nf = 0; nf < 4; ++nf) {
          float v = (ee ? acc1[mf][nf][r] : acc0[mf][nf][r]) + b1[ee][nf];
          v = v > 0.f ? v : 0.f;
          ssum += v * w2[ee][nf];
        }
        ssum += __shfl_xor(ssum, 1);
        ssum += __shfl_xor(ssum, 2);
        ssum += __shfl_xor(ssum, 4);
        ssum += __shfl_xor(ssum, 8);
        if ((lane & 15) == 0) {
          long row = row0 + wm * 64 + mf * 16 + ((lane >> 4) << 2) + r;
          atomicAdd(&out[(size_t)(2 * tp + ee) * B_DIM + row], ssum);
        }
      }
    }
}

// ---------------- launch -----------------------------------------------------
extern "C" void kernel_launch(void* const* d_in, const int* in_sizes, int n_in,
                              void* d_out, int out_size, void* d_ws, size_t ws_size,
                              hipStream_t stream) {
  const float* x    = (const float*)d_in[0];
  const float* gw   = (const float*)d_in[1];
  const float* expw = (const float*)d_in[2];
  const float* expb = (const float*)d_in[3];
  const float* tw1  = (const float*)d_in[4];
  const float* tb1  = (const float*)d_in[5];
  const float* tw2  = (const float*)d_in[6];
  const float* tb2  = (const float*)d_in[7];
  float* out = (float*)d_out;

  char* ws = (char*)d_ws;
  _Float16* xh  = (_Float16*)ws;  ws += (size_t)B_DIM * D_IN * 2;          // 32 MB
  _Float16* ewT = (_Float16*)ws;  ws += (size_t)N_EXPT * D_IN * D_EXP * 2; // 16 MB
  _Float16* t1T = (_Float16*)ws;  ws += (size_t)N_TASK * D_TOW * D_EXP * 2; // 4 MB
  _Float16* shh = (_Float16*)ws;  ws += (size_t)B_DIM * D_EXP * 2;         // 32 MB
  float* gates  = (float*)ws;     ws += (size_t)B_DIM * N_EXPT * 4;        // 0.5 MB

  prep_x_kernel<<<B_DIM, 256, 0, stream>>>(x, gw, xh, gates);
  transpose_cvt_kernel<<<dim3(D_EXP / 64, D_IN / 64, N_EXPT), 256, 0, stream>>>(
      expw, ewT, D_IN, D_EXP);
  transpose_cvt_kernel<<<dim3(D_TOW / 64, D_EXP / 64, N_TASK), 256, 0, stream>>>(
      tw1, t1T, D_EXP, D_TOW);
  init_out_kernel<<<(N_TASK * B_DIM + 255) / 256, 256, 0, stream>>>(out, tb2);
  moe_expert_kernel<<<dim3(B_DIM / 128, D_EXP / 128), 256, 0, stream>>>(
      xh, ewT, expb, gates, shh);
  moe_tower_kernel<<<dim3(B_DIM / 128, 8), 256, 0, stream>>>(
      shh, t1T, tb1, tw2, out);
}

// Round 15
// 371.670 us; speedup vs baseline: 1.0736x; 1.0736x over previous
//
#include <hip/hip_runtime.h>
#include <hip/hip_bf16.h>

#define B_DIM   16384
#define D_IN    1024
#define D_EXP   1024
#define D_TOW   512
#define N_EXPT  8
#define N_TASK  4

typedef _Float16 f16x8 __attribute__((ext_vector_type(8)));
typedef _Float16 f16x4 __attribute__((ext_vector_type(4)));
typedef float    f32x4 __attribute__((ext_vector_type(4)));

// ---------------- async global->LDS (16B per lane, wave-uniform LDS base) ---
__device__ __forceinline__ void gll16(const void* g, void* l) {
  __builtin_amdgcn_global_load_lds(
      (const __attribute__((address_space(1))) unsigned int*)g,
      (__attribute__((address_space(3))) unsigned int*)l,
      16, 0, 0);
}

// Fragment read from a swizzled [rows][64] f16 LDS tile (16x16x32 mapping).
// 16B chunk s within a 128B row holds global chunk s^(row&7).
__device__ __forceinline__ f16x8 ldfrag(const _Float16* sM, int rowbase, int ks, int lane) {
  int rl = rowbase + (lane & 15);
  int ch = ((ks << 2) + (lane >> 4)) ^ (rl & 7);
  return *(const f16x8*)&sM[rl * 64 + ch * 8];
}

#define FENCE asm volatile("" ::: "memory")

// ---------------- fused prep: prep_x + 2 transposes + init_out --------------
// Block ranges: [0,16384) prep_x | [16384,18432) expw transpose |
// [18432,18944) tw1 transpose | [18944,19200) init_out.
__global__ __launch_bounds__(256) void fused_prep_kernel(
    const float* __restrict__ x,    const float* __restrict__ gw,
    const float* __restrict__ expw, const float* __restrict__ tw1,
    const float* __restrict__ tb2,
    _Float16* __restrict__ xh, float* __restrict__ gates,
    _Float16* __restrict__ ewT, _Float16* __restrict__ t1T,
    float* __restrict__ out)
{
  __shared__ float smem[64 * 65];
  const int t = threadIdx.x;
  const int b = blockIdx.x;

  if (b < B_DIM) {
    // ---- prep_x: x row -> f16, gates row ----
    const long row = b;
    float4 v = ((const float4*)(x + row * D_IN))[t];
    f16x4 h;
    h[0] = (_Float16)v.x; h[1] = (_Float16)v.y;
    h[2] = (_Float16)v.z; h[3] = (_Float16)v.w;
    ((f16x4*)(xh + row * D_IN))[t] = h;

    float g[8];
#pragma unroll
    for (int e = 0; e < 8; ++e) g[e] = 0.f;
    const float* wp = gw + (size_t)t * 4 * 8;
    float xs[4] = {v.x, v.y, v.z, v.w};
#pragma unroll
    for (int j = 0; j < 4; ++j)
#pragma unroll
      for (int e = 0; e < 8; ++e) g[e] += xs[j] * wp[j * 8 + e];

#pragma unroll
    for (int e = 0; e < 8; ++e) {
      g[e] += __shfl_xor(g[e], 1);  g[e] += __shfl_xor(g[e], 2);
      g[e] += __shfl_xor(g[e], 4);  g[e] += __shfl_xor(g[e], 8);
      g[e] += __shfl_xor(g[e], 16); g[e] += __shfl_xor(g[e], 32);
    }
    if ((t & 63) == 0) {
#pragma unroll
      for (int e = 0; e < 8; ++e) smem[(t >> 6) * 8 + e] = g[e];
    }
    __syncthreads();
    if (t < 8)
      gates[row * 8 + t] = smem[t] + smem[8 + t] + smem[16 + t] + smem[24 + t];
  } else if (b < B_DIM + 2048 + 512) {
    // ---- tiled transpose + cvt: in[s][K][N] -> out[s][N][K] ----
    const float* in; _Float16* op_base; int K, N, bx, by, bz;
    if (b < B_DIM + 2048) {
      int i = b - B_DIM;
      bx = i & 15; by = (i >> 4) & 15; bz = i >> 8;
      in = expw; op_base = ewT; K = D_IN; N = D_EXP;
    } else {
      int i = b - B_DIM - 2048;
      bx = i & 7; by = (i >> 3) & 15; bz = i >> 7;
      in = tw1; op_base = t1T; K = D_EXP; N = D_TOW;
    }
    float (*tile)[65] = (float(*)[65])smem;
    const int tx = t & 63, ty = t >> 6;
    const int n0 = bx * 64, k0 = by * 64;
    const float* ip = in + (long)bz * K * N;
    _Float16* op = op_base + (long)bz * K * N;
#pragma unroll
    for (int i = 0; i < 16; ++i) {
      int r = ty * 16 + i;
      tile[r][tx] = ip[(long)(k0 + r) * N + n0 + tx];
    }
    __syncthreads();
#pragma unroll
    for (int i = 0; i < 16; ++i) {
      int r = ty * 16 + i;
      op[(long)(n0 + r) * K + k0 + tx] = (_Float16)tile[tx][r];
    }
  } else {
    // ---- init_out with tb2 ----
    int i = (b - B_DIM - 2048 - 512) * 256 + t;
    if (i < N_TASK * B_DIM) out[i] = tb2[i >> 14];
  }
}

// ============ expert-pair kernel (r12 structure, relaxed acc0 scheduling) ===
// BM=256, BN=128, BK=64; 8 waves (4M x 2N); per-wave C = 64x64 PER EXPERT,
// two experts resident (B0,B1 share one A). 64 MFMA / 24 ds_read per K-tile.
// Per tile: reads AF+B0 -> acc0 MFMA (compiler-counted lgkm waits) -> reads
// B1 -> lgkm(0) -> BARRIER#1 (all CUR reads done block-wide) -> STAGE tile+2
// into CUR (overlaps acc1 MFMA) -> vmcnt(8) -> BARRIER#2.
// Slot layout (f16 idx): A[256x64]@0, B0[128x64]@16384, B1@24576.

#define LD_AF                                                                  \
    _Pragma("unroll") for (int mf = 0; mf < 4; ++mf)                           \
      _Pragma("unroll") for (int ks = 0; ks < 2; ++ks)                         \
        af[mf][ks] = ldfrag(sA, (wm & 1) * 64 + mf * 16, ks, lane)

#define LD_BF(SB)                                                              \
    _Pragma("unroll") for (int nf = 0; nf < 4; ++nf)                           \
      _Pragma("unroll") for (int ks = 0; ks < 2; ++ks)                         \
        bf[nf][ks] = ldfrag(SB, nf * 16, ks, lane)

#define MFMA32(ACC)                                                            \
    _Pragma("unroll") for (int mf = 0; mf < 4; ++mf)                           \
      _Pragma("unroll") for (int nf = 0; nf < 4; ++nf)                         \
        _Pragma("unroll") for (int ks = 0; ks < 2; ++ks)                       \
          ACC[mf][nf] = __builtin_amdgcn_mfma_f32_16x16x32_f16(                \
              af[mf][ks], bf[nf][ks], ACC[mf][nf], 0, 0, 0)

// ---------------- fused experts + gate-weighted combine ---------------------
// shared[b,d] = sum_e gates[b,e] * relu(x[b,:] @ exp_w[e,:,d] + exp_b[e,d])
__global__ __launch_bounds__(512, 2) void moe_expert_kernel(
    const _Float16* __restrict__ xh,    // [B,1024]
    const _Float16* __restrict__ ewT,   // [8][n=1024][k=1024]
    const float* __restrict__ expb,     // [8][1024]
    const float* __restrict__ gates,    // [B][8]
    _Float16* __restrict__ shout)       // [B,1024] f16
{
  __shared__ alignas(16) _Float16 sT2[2][32768];  // 128KB (64KB per slot)
  __shared__ float sG[256 * 8];                   // 8KB
  __shared__ _Float16 sBiasH[8 * 128];            // 2KB
  const int t = threadIdx.x;
  const int lane = t & 63;
  const int wave = t >> 6;
  const int wm = wave >> 1, wn = wave & 1;
  const long row0 = (long)blockIdx.x * 256;
  const int col0 = blockIdx.y * 128;

  for (int i = t; i < 256 * 8; i += 512) sG[i] = gates[row0 * 8 + i];
  for (int i = t; i < 8 * 128; i += 512)
    sBiasH[i] = (_Float16)expb[(i >> 7) * D_EXP + col0 + (i & 127)];

  const int so_t = (((t & 7) ^ ((t >> 3) & 7)) << 4);
  const char* aBase = (const char*)xh + row0 * 2048 + (size_t)(t >> 3) * 2048 + so_t;
  const char* bRoot = (const char*)ewT + (size_t)col0 * 2048 + (size_t)(t >> 3) * 2048 + so_t;

  auto SA = [&](int S, int kt) {                  // A k-step: 4 gll16
    const char* g = aBase + (size_t)(kt & 15) * 128;
    char* d = (char*)&sT2[S][0] + t * 16;
    gll16(g, d);                  gll16(g + 131072, d + 8192);
    gll16(g + 262144, d + 16384); gll16(g + 393216, d + 24576);
    FENCE;
  };
  auto SB = [&](int S, int eloc, int e, int kt) { // one expert's B: 2 gll16
    const char* g = bRoot + (size_t)e * 2097152 + (size_t)(kt & 15) * 128;
    char* d = (char*)&sT2[S][0] + 32768 + eloc * 16384 + t * 16;
    gll16(g, d); gll16(g + 131072, d + 8192);
    FENCE;
  };
  auto STAGE = [&](int S, int tau) {
    const int ep = tau >> 4, kt = tau & 15;
    SA(S, kt);
    SB(S, 0, 2 * ep, kt);
    SB(S, 1, 2 * ep + 1, kt);
  };

  __syncthreads();   // sG/sBias visible; vmcnt fully drained -> clean FIFO

  STAGE(0, 0);
  STAGE(1, 1);
  asm volatile("s_waitcnt vmcnt(8)" ::: "memory");   // tile 0 landed
  __builtin_amdgcn_s_barrier();
  FENCE;

  f32x4 acc0[4][4] = {};
  f32x4 acc1[4][4] = {};
  f16x4 shacc[4][4] = {};
  f16x8 af[4][2], bf[4][2];

#define TILE_E(CUR, TAU)                                                       \
  do {                                                                         \
    const int tau_ = (TAU);                                                    \
    const _Float16* sA  = &sT2[CUR][(wm >> 1) * 8192];                         \
    const _Float16* sB0 = &sT2[CUR][16384 + wn * 4096];                        \
    const _Float16* sB1 = &sT2[CUR][24576 + wn * 4096];                        \
    LD_AF; LD_BF(sB0);                                                         \
    __builtin_amdgcn_s_setprio(1);                                             \
    MFMA32(acc0);                        /* compiler-counted lgkm waits */     \
    __builtin_amdgcn_s_setprio(0);                                             \
    LD_BF(sB1);                                                                \
    asm volatile("s_waitcnt lgkmcnt(0)" ::: "memory");                         \
    __builtin_amdgcn_sched_barrier(0);                                         \
    FENCE;                                                                     \
    __builtin_amdgcn_s_barrier();        /* all waves drained CUR reads */     \
    FENCE;                                                                     \
    if (tau_ < 62) STAGE(CUR, tau_ + 2); /* overlaps acc1 MFMA cluster */      \
    __builtin_amdgcn_s_setprio(1);                                             \
    MFMA32(acc1);                                                              \
    __builtin_amdgcn_s_setprio(0);                                             \
    FENCE;                                                                     \
    if (tau_ < 62)      { asm volatile("s_waitcnt vmcnt(8)" ::: "memory"); }   \
    else if (tau_ == 62){ asm volatile("s_waitcnt vmcnt(0)" ::: "memory"); }   \
    if (tau_ < 63) { __builtin_amdgcn_s_barrier(); FENCE; }                    \
    if ((tau_ & 15) == 15) {             /* combine both experts */            \
      const int e0 = (tau_ >> 4) * 2;                                          \
      _Pragma("unroll") for (int ee = 0; ee < 2; ++ee) {                       \
        const int e = e0 + ee;                                                 \
        float bias4[4];                                                        \
        _Pragma("unroll") for (int nf = 0; nf < 4; ++nf)                       \
          bias4[nf] = (float)sBiasH[e * 128 + wn * 64 + nf * 16 + (lane & 15)];\
        _Pragma("unroll") for (int mf = 0; mf < 4; ++mf) {                     \
          int rbase = wm * 64 + mf * 16 + ((lane >> 4) << 2);                  \
          float gv[4];                                                         \
          _Pragma("unroll") for (int r = 0; r < 4; ++r)                        \
            gv[r] = sG[(rbase + r) * 8 + e];                                   \
          _Pragma("unroll") for (int nf = 0; nf < 4; ++nf) {                   \
            f16x4 sh = shacc[mf][nf];                                          \
            _Pragma("unroll") for (int r = 0; r < 4; ++r) {                    \
              float hv = (ee ? acc1[mf][nf][r] : acc0[mf][nf][r]) + bias4[nf]; \
              hv = hv > 0.f ? hv : 0.f;                                        \
              sh[r] += (_Float16)(gv[r] * hv);                                 \
              if (ee) acc1[mf][nf][r] = 0.f; else acc0[mf][nf][r] = 0.f;       \
            }                                                                  \
            shacc[mf][nf] = sh;                                                \
          }                                                                    \
        }                                                                      \
      }                                                                        \
    }                                                                          \
  } while (0)

  for (int tb = 0; tb < 64; tb += 2) {
    TILE_E(0, tb);
    TILE_E(1, tb + 1);
  }
#undef TILE_E

  // write shared tile as f16
#pragma unroll
  for (int mf = 0; mf < 4; ++mf)
#pragma unroll
    for (int r = 0; r < 4; ++r) {
      long row = row0 + wm * 64 + mf * 16 + ((lane >> 4) << 2) + r;
      _Float16* op = shout + row * D_EXP + col0 + wn * 64 + (lane & 15);
#pragma unroll
      for (int nf = 0; nf < 4; ++nf) op[nf * 16] = shacc[mf][nf][r];
    }
}

// ---------------- fused towers (2 tasks resident, shared A) -----------------
// out[task,b] += sum_h relu(shared[b,:] @ tw1[task,:,h] + tb1[task,h]) * tw2[task,h]
// Grid: (64, 8); y -> tp = y>>2 (0..1 => tasks 2tp,2tp+1), col0 = (y&3)*128.
__global__ __launch_bounds__(512, 2) void moe_tower_kernel(
    const _Float16* __restrict__ sh,    // [B,1024] f16
    const _Float16* __restrict__ t1T,   // [4][h=512][d=1024] f16
    const float* __restrict__ tb1,      // [4][512]
    const float* __restrict__ tw2,      // [4][512]
    float* __restrict__ out)            // [4][B]
{
  __shared__ alignas(16) _Float16 sT2[2][32768];  // 128KB
  const int t = threadIdx.x;
  const int lane = t & 63;
  const int wave = t >> 6;
  const int wm = wave >> 1, wn = wave & 1;
  const long row0 = (long)blockIdx.x * 256;
  const int tp = blockIdx.y >> 2;                 // 0..1: tasks 2tp, 2tp+1
  const int col0 = (blockIdx.y & 3) * 128;

  float b1[2][4], w2[2][4];
#pragma unroll
  for (int ee = 0; ee < 2; ++ee)
#pragma unroll
    for (int nf = 0; nf < 4; ++nf) {
      int col = col0 + wn * 64 + nf * 16 + (lane & 15);
      b1[ee][nf] = tb1[(2 * tp + ee) * D_TOW + col];
      w2[ee][nf] = tw2[(2 * tp + ee) * D_TOW + col];
    }
  asm volatile("s_waitcnt vmcnt(0)" ::: "memory");  // clean FIFO

  const int so_t = (((t & 7) ^ ((t >> 3) & 7)) << 4);
  const char* aBase = (const char*)sh + row0 * 2048 + (size_t)(t >> 3) * 2048 + so_t;
  const char* bRoot = (const char*)t1T + (size_t)col0 * 2048
                      + (size_t)(t >> 3) * 2048 + so_t;

  auto SA = [&](int S, int kt) {
    const char* g = aBase + (size_t)kt * 128;
    char* d = (char*)&sT2[S][0] + t * 16;
    gll16(g, d);                  gll16(g + 131072, d + 8192);
    gll16(g + 262144, d + 16384); gll16(g + 393216, d + 24576);
    FENCE;
  };
  auto SB = [&](int S, int eloc, int task, int kt) {
    const char* g = bRoot + (size_t)task * 1048576 + (size_t)kt * 128;
    char* d = (char*)&sT2[S][0] + 32768 + eloc * 16384 + t * 16;
    gll16(g, d); gll16(g + 131072, d + 8192);
    FENCE;
  };
  auto STAGE = [&](int S, int kt) {
    SA(S, kt);
    SB(S, 0, 2 * tp, kt);
    SB(S, 1, 2 * tp + 1, kt);
  };

  __syncthreads();

  STAGE(0, 0);
  STAGE(1, 1);
  asm volatile("s_waitcnt vmcnt(8)" ::: "memory");
  __builtin_amdgcn_s_barrier();
  FENCE;

  f32x4 acc0[4][4] = {};
  f32x4 acc1[4][4] = {};
  f16x8 af[4][2], bf[4][2];

#define TILE_T(CUR, TAU)                                                       \
  do {                                                                         \
    const int tau_ = (TAU);                                                    \
    const _Float16* sA  = &sT2[CUR][(wm >> 1) * 8192];                         \
    const _Float16* sB0 = &sT2[CUR][16384 + wn * 4096];                        \
    const _Float16* sB1 = &sT2[CUR][24576 + wn * 4096];                        \
    LD_AF; LD_BF(sB0);                                                         \
    __builtin_amdgcn_s_setprio(1);                                             \
    MFMA32(acc0);                                                              \
    __builtin_amdgcn_s_setprio(0);                                             \
    LD_BF(sB1);                                                                \
    asm volatile("s_waitcnt lgkmcnt(0)" ::: "memory");                         \
    __builtin_amdgcn_sched_barrier(0);                                         \
    FENCE;                                                                     \
    __builtin_amdgcn_s_barrier();                                              \
    FENCE;                                                                     \
    if (tau_ < 14) STAGE(CUR, tau_ + 2);                                       \
    __builtin_amdgcn_s_setprio(1);                                             \
    MFMA32(acc1);                                                              \
    __builtin_amdgcn_s_setprio(0);                                             \
    FENCE;                                                                     \
    if (tau_ < 14)      { asm volatile("s_waitcnt vmcnt(8)" ::: "memory"); }   \
    else if (tau_ == 14){ asm volatile("s_waitcnt vmcnt(0)" ::: "memory"); }   \
    if (tau_ < 15) { __builtin_amdgcn_s_barrier(); FENCE; }                    \
  } while (0)

  for (int tb = 0; tb < 16; tb += 2) {
    TILE_T(0, tb);
    TILE_T(1, tb + 1);
  }
#undef TILE_T

#pragma unroll
  for (int mf = 0; mf < 4; ++mf)
#pragma unroll
    for (int r = 0; r < 4; ++r) {
#pragma unroll
      for (int ee = 0; ee < 2; ++ee) {
        float ssum = 0.f;
#pragma unroll
        for (int nf = 0; nf < 4; ++nf) {
          float v = (ee ? acc1[mf][nf][r] : acc0[mf][nf][r]) + b1[ee][nf];
          v = v > 0.f ? v : 0.f;
          ssum += v * w2[ee][nf];
        }
        ssum += __shfl_xor(ssum, 1);
        ssum += __shfl_xor(ssum, 2);
        ssum += __shfl_xor(ssum, 4);
        ssum += __shfl_xor(ssum, 8);
        if ((lane & 15) == 0) {
          long row = row0 + wm * 64 + mf * 16 + ((lane >> 4) << 2) + r;
          atomicAdd(&out[(size_t)(2 * tp + ee) * B_DIM + row], ssum);
        }
      }
    }
}

// ---------------- launch -----------------------------------------------------
extern "C" void kernel_launch(void* const* d_in, const int* in_sizes, int n_in,
                              void* d_out, int out_size, void* d_ws, size_t ws_size,
                              hipStream_t stream) {
  const float* x    = (const float*)d_in[0];
  const float* gw   = (const float*)d_in[1];
  const float* expw = (const float*)d_in[2];
  const float* expb = (const float*)d_in[3];
  const float* tw1  = (const float*)d_in[4];
  const float* tb1  = (const float*)d_in[5];
  const float* tw2  = (const float*)d_in[6];
  const float* tb2  = (const float*)d_in[7];
  float* out = (float*)d_out;

  char* ws = (char*)d_ws;
  _Float16* xh  = (_Float16*)ws;  ws += (size_t)B_DIM * D_IN * 2;          // 32 MB
  _Float16* ewT = (_Float16*)ws;  ws += (size_t)N_EXPT * D_IN * D_EXP * 2; // 16 MB
  _Float16* t1T = (_Float16*)ws;  ws += (size_t)N_TASK * D_TOW * D_EXP * 2; // 4 MB
  _Float16* shh = (_Float16*)ws;  ws += (size_t)B_DIM * D_EXP * 2;         // 32 MB
  float* gates  = (float*)ws;     ws += (size_t)B_DIM * N_EXPT * 4;        // 0.5 MB

  // fused prep: 16384 (prep_x) + 2048 (expw T) + 512 (tw1 T) + 256 (init_out)
  fused_prep_kernel<<<19200, 256, 0, stream>>>(
      x, gw, expw, tw1, tb2, xh, gates, ewT, t1T, out);
  moe_expert_kernel<<<dim3(B_DIM / 256, D_EXP / 128), 512, 0, stream>>>(
      xh, ewT, expb, gates, shh);
  moe_tower_kernel<<<dim3(B_DIM / 256, 8), 512, 0, stream>>>(
      shh, t1T, tb1, tw2, out);
}